// Round 12
// baseline (2393.094 us; speedup 1.0000x reference)
//
#include <hip/hip_runtime.h>
#include <hip/hip_bf16.h>
#include <cstdint>
#include <cstddef>

typedef __bf16 bf16_t;
typedef __bf16 bf16x4 __attribute__((ext_vector_type(4)));
typedef __bf16 bf16x8 __attribute__((ext_vector_type(8)));
typedef float f32x4 __attribute__((ext_vector_type(4)));

#define GLD16(src, dst)                                                       \
    __builtin_amdgcn_global_load_lds(                                         \
        (const __attribute__((address_space(1))) void*)(src),                 \
        (__attribute__((address_space(3))) void*)(dst), 16, 0, 0)

// s_barrier WITH compiler memory fence (R8 lesson).
#define BAR() asm volatile("s_barrier" ::: "memory")
#define WAIT_VM3() asm volatile("s_waitcnt vmcnt(3)" ::: "memory")
#define WAIT_VM2() asm volatile("s_waitcnt vmcnt(2)" ::: "memory")
#define WAIT_VM0() asm volatile("s_waitcnt vmcnt(0)" ::: "memory")

// ---------------------------------------------------------------------------
// x fp32 -> bf16, vectorized (G13)
// ---------------------------------------------------------------------------
__global__ __launch_bounds__(256) void cvt_x_kernel(const float* __restrict__ x,
                                                    bf16_t* __restrict__ xb, int n4) {
    int idx = blockIdx.x * blockDim.x + threadIdx.x;
    int stride = gridDim.x * blockDim.x;
    const f32x4* xv = (const f32x4*)x;
    bf16x4* ov = (bf16x4*)xb;
    for (int i = idx; i < n4; i += stride) {
        f32x4 v = xv[i];
        bf16x4 o;
        o[0] = (bf16_t)v[0];
        o[1] = (bf16_t)v[1];
        o[2] = (bf16_t)v[2];
        o[3] = (bf16_t)v[3];
        ov[i] = o;
    }
}

// ---------------------------------------------------------------------------
// Build Mt[n][k] (bf16, [N][K]) from the quaternion Hamilton block structure.
// ---------------------------------------------------------------------------
__global__ __launch_bounds__(256) void pack_w_kernel(const float* __restrict__ Wa,
                                                     const float* __restrict__ Wb,
                                                     const float* __restrict__ Wc,
                                                     const float* __restrict__ Wd,
                                                     bf16_t* __restrict__ Mt) {
    __shared__ float tile[64][65];
    const int kb = blockIdx.x * 64;
    const int nb = blockIdx.y * 64;
    const int i = kb >> 10;
    const int j = nb >> 10;

    const float* W[4] = {Wa, Wb, Wc, Wd};
    const int srcIdx[4][4] = {{0, 1, 2, 3}, {1, 0, 3, 2}, {2, 3, 0, 1}, {3, 2, 1, 0}};
    const float sgn[4][4] = {{1.f, 1.f, 1.f, 1.f},
                             {-1.f, 1.f, -1.f, 1.f},
                             {-1.f, 1.f, 1.f, -1.f},
                             {-1.f, -1.f, 1.f, 1.f}};
    const float* Ws = W[srcIdx[i][j]];
    const float s = sgn[i][j];

    const int kq = kb & 1023;
    const int nq = nb & 1023;
    const int tx = threadIdx.x & 63;
    const int ty = threadIdx.x >> 6;

    for (int r = ty; r < 64; r += 4)
        tile[r][tx] = Ws[(size_t)(kq + r) * 1024 + (nq + tx)];
    __syncthreads();
    for (int r = ty; r < 64; r += 4)
        Mt[(size_t)(nb + r) * 4096 + (kb + tx)] = (bf16_t)(s * tile[tx][r]);
}

// ---------------------------------------------------------------------------
// 256x256 GEMM, BK=32, 2 blocks/CU: C = A[M][K] * Bt[N][K]^T + bias.
// 512 threads = 8 waves (2Mx4N), each owns 128x64.
// R11 model: at 128KB LDS = 1 block/CU, MFMA pipe (2483cy) and LDS-read pipe
// (2304cy) SERIALIZE inside one barrier-lockstepped block (measured 4575).
// Fix = inter-block TLP (m114): halve BK -> LDS 64KB -> 2 blocks/CU; block B
// issues MFMA while block A sits at barriers/LDS and vice versa.
// LDS 64 KiB: A dbuf [0,32K), B dbuf [32K,64K); half-tile = [128 rows][32 k]
// = 8KB, row = 64B.  Swizzle (re-derived for 64B rows): LDS 16B-slot s at row
// r holds global k-chunk s ^ ((r>>1)&3).  Stage: linear gload_lds dest, lane
// (row=lane>>2, s=lane&3) fetches global kb = (lane&3)^((lane>>3)&3).  Read:
// k-chunk c=l4 at row R -> slot l4 ^ ((R>>1)&3) (R's frag-base bits vanish
// mod 4 -> slot = l4 ^ ((l15>>1)&3)).  Bank audit: each bank gets exactly 2
// lanes (rows r,r+8) = 2-way = free (m136).
//
// Schedule = R10's proven protocol, counts halved (1 GLD per stage call):
//   p0: stage Ah1(t+1,idle) |BAR| rd amh0-m23; mmac00; rd b1          |BAR|
//   p1: stage Bh0(t+2,live) |BAR| mmac01; rd amh1-m01                 |BAR|
//   p2: stage Bh1(t+2,live) |BAR| rd amh1-m23; mmac11; VM2(/VM0)      |BAR|
//   p3: stage Ah0(t+2,live) |BAR| mmac10; shadow rd b0,amh0-m01 (t+1) |BAR|
// Ledger: entering t outstanding = {Bh0,Bh1,Ah0}(t+1); p0..p2 add 3 -> 6;
// VM2@p2 leaves {Bh0,Bh1(t+2)}, drains ALL of t+1 -> BAR -> p3 shadow reads
// sound for every wave (R9 protocol: issuer-drain + common barrier).
// WAR: every staged region's reads are consumed by an MFMA >=1 barrier before
// the stage issue (MFMA issue implies operand ds_reads completed).
// Tail: VM0 at p2 when tt+2>=NT; no stages/shadow when indices exceed NT.
// ---------------------------------------------------------------------------
__global__ __launch_bounds__(512, 4) void qgemm_kernel(const bf16_t* __restrict__ A,
                                                       const bf16_t* __restrict__ Bt,
                                                       const float* __restrict__ bias,
                                                       float* __restrict__ C) {
    constexpr int N = 4096, K = 4096;
    constexpr int NT = K / 32;
    extern __shared__ __align__(16) char lds[];

    const int tid = threadIdx.x;
    const int w = tid >> 6;
    const int lane = tid & 63;
    const int l15 = lane & 15, l4 = lane >> 4;
    const int wr = w >> 2, wc = w & 3;  // 2 x 4 wave grid

    // XCD-aware swizzle (512 = 8*64, bijective)
    const int wg = blockIdx.x;
    const int swz = (wg & 7) * 64 + (wg >> 3);
    const int brow = (swz >> 4) * 256;  // 32 tile rows
    const int bcol = (swz & 15) * 256;  // 16 tile cols

    // staging perm: lane covers (row = w*16 + (lane>>2), slot = lane&3);
    // global k-chunk = (lane&3) ^ ((lane>>3)&3)  [inverse of read swizzle]
    const int srow = lane >> 2;
    const int skb = (lane & 3) ^ ((lane >> 3) & 3);
    // read swizzle slot for k-chunk l4: l4 ^ ((l15>>1)&3)
    const int rslot = (l4 ^ ((l15 >> 1) & 3)) & 3;

    auto stageA = [&](int buf, int h, int tt) {
        const bf16_t* src = A + (size_t)(brow + h * 128 + w * 16 + srow) * K +
                            tt * 32 + skb * 8;
        GLD16(src, lds + buf * 16384 + h * 8192 + w * 1024);
    };
    auto stageB = [&](int buf, int h, int tt) {
        const bf16_t* src = Bt + (size_t)(bcol + h * 128 + w * 16 + srow) * K +
                            tt * 32 + skb * 8;
        GLD16(src, lds + 32768 + buf * 16384 + h * 8192 + w * 1024);
    };

    f32x4 acc[8][4] = {};
    bf16x8 a[4], b0[2], b1[2];

    // one A m-frag (1 read): A rows of this wave live in half h = wr
    auto ldAm = [&](int buf, int mh, int m) {
        a[m] = *(const bf16x8*)(lds + buf * 16384 + wr * 8192 +
                                (mh * 64 + m * 16 + l15) * 64 + rslot * 16);
    };
    // B frags: nh selects the STAGING half; wave cols = nh*128 + wc*32 + n*16
    auto ldB = [&](int buf, int nh, bf16x8(&b)[2]) {
#pragma unroll
        for (int n = 0; n < 2; ++n)
            b[n] = *(const bf16x8*)(lds + 32768 + buf * 16384 + nh * 8192 +
                                    (wc * 32 + n * 16 + l15) * 64 + rslot * 16);
    };
    auto mmac = [&](int mh, int nh, bf16x8(&b)[2]) {
        __builtin_amdgcn_s_setprio(1);
#pragma unroll
        for (int m = 0; m < 4; ++m)
#pragma unroll
            for (int n = 0; n < 2; ++n)
                acc[mh * 4 + m][nh * 2 + n] = __builtin_amdgcn_mfma_f32_16x16x32_bf16(
                    a[m], b[n], acc[mh * 4 + m][nh * 2 + n], 0, 0, 0);
        __builtin_amdgcn_s_setprio(0);
    };

    // prologue: tile0 full (4 loads, buf0) + tile1's Bh0/Bh1/Ah0 (3, buf1);
    // VM3 drains tile0, leaves tile1's trio; BAR; preload b0/amh0-m01.
    stageA(0, 0, 0);
    stageA(0, 1, 0);
    stageB(0, 0, 0);
    stageB(0, 1, 0);
    stageB(1, 0, 1);
    stageB(1, 1, 1);
    stageA(1, 0, 1);
    WAIT_VM3();
    BAR();
    ldB(0, 0, b0);
    ldAm(0, 0, 0);
    ldAm(0, 0, 1);

    for (int tt = 0; tt < NT; ++tt) {
        const int cur = tt & 1;
        // phase 0: (mh0,nh0); stage A h1 of t+1 (idle buf)
        if (tt + 1 < NT) stageA(cur ^ 1, 1, tt + 1);
        BAR();
        ldAm(cur, 0, 2);
        ldAm(cur, 0, 3);
        mmac(0, 0, b0);
        ldB(cur, 1, b1);
        BAR();
        // phase 1: (mh0,nh1); stage B h0 of t+2 (live buf)
        if (tt + 2 < NT) stageB(cur, 0, tt + 2);
        BAR();
        mmac(0, 1, b1);
        ldAm(cur, 1, 0);
        ldAm(cur, 1, 1);
        BAR();
        // phase 2: (mh1,nh1); stage B h1 of t+2 (live buf); counted drain
        if (tt + 2 < NT) stageB(cur, 1, tt + 2);
        BAR();
        ldAm(cur, 1, 2);
        ldAm(cur, 1, 3);
        mmac(1, 1, b1);
        if (tt + 2 < NT) {
            WAIT_VM2();  // leaves Bh0/Bh1(t+2); ALL of t+1 landed
        } else {
            WAIT_VM0();  // tail
        }
        BAR();
        // phase 3: (mh1,nh0); stage A h0 of t+2 (live buf); shadow preload t+1
        if (tt + 2 < NT) stageA(cur, 0, tt + 2);
        BAR();
        mmac(1, 0, b0);
        if (tt + 1 < NT) {
            ldB(cur ^ 1, 0, b0);
            ldAm(cur ^ 1, 0, 0);
            ldAm(cur ^ 1, 0, 1);
        }
        BAR();
    }

    // epilogue: C/D layout col = lane&15, row = (lane>>4)*4 + i.
    // B mapping: global n -> col = (n>>1)*128 + wc*32 + (n&1)*16
#pragma unroll
    for (int n = 0; n < 4; ++n) {
        const int col = bcol + (n >> 1) * 128 + wc * 32 + (n & 1) * 16 + l15;
        const float bv = bias[col];
#pragma unroll
        for (int m = 0; m < 8; ++m) {
            const int row0 = brow + wr * 128 + m * 16 + l4 * 4;
            const f32x4 v = acc[m][n];
#pragma unroll
            for (int i = 0; i < 4; ++i)
                C[(size_t)(row0 + i) * N + col] = v[i] + bv;
        }
    }
}

// ---------------------------------------------------------------------------
extern "C" void kernel_launch(void* const* d_in, const int* in_sizes, int n_in,
                              void* d_out, int out_size, void* d_ws, size_t ws_size,
                              hipStream_t stream) {
    const float* x = (const float*)d_in[0];
    const float* Wa = (const float*)d_in[1];
    const float* Wb = (const float*)d_in[2];
    const float* Wc = (const float*)d_in[3];
    const float* Wd = (const float*)d_in[4];
    const float* bias = (const float*)d_in[5];
    float* out = (float*)d_out;

    const int M = 8192, N = 4096, K = 4096;

    bf16_t* xb = (bf16_t*)d_ws;       // [M][K] bf16
    bf16_t* Mt = xb + (size_t)M * K;  // [N][K] bf16

    cvt_x_kernel<<<4096, 256, 0, stream>>>(x, xb, (M * K) / 4);
    pack_w_kernel<<<dim3(64, 64), 256, 0, stream>>>(Wa, Wb, Wc, Wd, Mt);

    (void)hipFuncSetAttribute((const void*)qgemm_kernel,
                              hipFuncAttributeMaxDynamicSharedMemorySize, 65536);
    qgemm_kernel<<<dim3((M / 256) * (N / 256)), 512, 65536, stream>>>(xb, Mt, bias, out);
}

// Round 13
// 315.659 us; speedup vs baseline: 7.5813x; 7.5813x over previous
//
#include <hip/hip_runtime.h>
#include <hip/hip_bf16.h>
#include <cstdint>
#include <cstddef>

typedef __bf16 bf16_t;
typedef __bf16 bf16x8 __attribute__((ext_vector_type(8)));
typedef float f32x4 __attribute__((ext_vector_type(4)));

#define GLD16(src, dst)                                                       \
    __builtin_amdgcn_global_load_lds(                                         \
        (const __attribute__((address_space(1))) void*)(src),                 \
        (__attribute__((address_space(3))) void*)(dst), 16, 0, 0)

// s_barrier WITH compiler memory fence (R8 lesson).
#define BAR() asm volatile("s_barrier" ::: "memory")
#define WAIT_VM4() asm volatile("s_waitcnt vmcnt(4)" ::: "memory")
#define WAIT_VM2() asm volatile("s_waitcnt vmcnt(2)" ::: "memory")
#define WAIT_VM0() asm volatile("s_waitcnt vmcnt(0)" ::: "memory")

// ---------------------------------------------------------------------------
// x fp32 -> bf16, PANEL-MAJOR: xbT[k/32][row][32].  Each thread converts one
// row x 32-k chunk: reads 128B (full lines, per-thread contiguous), writes
// 64B contiguous across consecutive threads (row-fast index).
// ---------------------------------------------------------------------------
__global__ __launch_bounds__(256) void cvt_x_kernel(const float* __restrict__ x,
                                                    bf16_t* __restrict__ xbT) {
    constexpr int M = 8192, K = 4096;
    int i = blockIdx.x * blockDim.x + threadIdx.x;  // row-fast: i = p*M + row
    const int total = M * (K / 32);
    const int stride = gridDim.x * blockDim.x;
    for (; i < total; i += stride) {
        const int row = i & (M - 1);
        const int p = i >> 13;  // M = 2^13
        const f32x4* src = (const f32x4*)(x + (size_t)row * K + p * 32);
        bf16_t* dst = xbT + (size_t)p * M * 32 + (size_t)row * 32;
#pragma unroll
        for (int c = 0; c < 4; ++c) {
            const f32x4 v0 = src[c * 2], v1 = src[c * 2 + 1];
            bf16x8 o;
            o[0] = (bf16_t)v0[0]; o[1] = (bf16_t)v0[1];
            o[2] = (bf16_t)v0[2]; o[3] = (bf16_t)v0[3];
            o[4] = (bf16_t)v1[0]; o[5] = (bf16_t)v1[1];
            o[6] = (bf16_t)v1[2]; o[7] = (bf16_t)v1[3];
            *(bf16x8*)(dst + c * 8) = o;
        }
    }
}

// ---------------------------------------------------------------------------
// Build MtT (bf16, PANEL-MAJOR [k/32][n][32]) from the Hamilton structure.
// ---------------------------------------------------------------------------
__global__ __launch_bounds__(256) void pack_w_kernel(const float* __restrict__ Wa,
                                                     const float* __restrict__ Wb,
                                                     const float* __restrict__ Wc,
                                                     const float* __restrict__ Wd,
                                                     bf16_t* __restrict__ MtT) {
    __shared__ float tile[64][65];
    const int kb = blockIdx.x * 64;
    const int nb = blockIdx.y * 64;
    const int i = kb >> 10;
    const int j = nb >> 10;

    const float* W[4] = {Wa, Wb, Wc, Wd};
    const int srcIdx[4][4] = {{0, 1, 2, 3}, {1, 0, 3, 2}, {2, 3, 0, 1}, {3, 2, 1, 0}};
    const float sgn[4][4] = {{1.f, 1.f, 1.f, 1.f},
                             {-1.f, 1.f, -1.f, 1.f},
                             {-1.f, 1.f, 1.f, -1.f},
                             {-1.f, -1.f, 1.f, 1.f}};
    const float* Ws = W[srcIdx[i][j]];
    const float s = sgn[i][j];

    const int kq = kb & 1023;
    const int nq = nb & 1023;
    const int tx = threadIdx.x & 63;
    const int ty = threadIdx.x >> 6;

    for (int r = ty; r < 64; r += 4)
        tile[r][tx] = Ws[(size_t)(kq + r) * 1024 + (nq + tx)];
    __syncthreads();
    for (int r = ty; r < 64; r += 4) {
        const int k = kb + tx;
        const int n = nb + r;
        MtT[(size_t)(k >> 5) * (4096 * 32) + (size_t)n * 32 + (k & 31)] =
            (bf16_t)(s * tile[tx][r]);
    }
}

// ---------------------------------------------------------------------------
// 256x128 GEMM, BK=32, 4 waves, 2 blocks/CU: C = A*Mt^T + bias.
// 256 threads = 4 waves (2Mx2N), per-wave 128x64 (same geometry as R10).
// R12 lesson: launch_bounds(512,4) capped VGPR at 128 -> acc spilled ->
// 6.5GB scratch writes.  Here: 4-wave block, launch_bounds(256,2) -> cap 256,
// need ~190 -> no spill; LDS 48KB -> 2 blocks/CU -> m114 inter-block TLP
// (two independent barrier domains interleave LDS and MFMA pipes).
// Operands PANEL-MAJOR [k/32][row][32]: each staged half is one contiguous
// 4KB (B) / 2x4KB (A) chunk -> full-line fetches, no 64B waste (R12's 15x
// overfetch had this + spill traffic).
// LDS 48KB: A dbuf [0,32K) (16KB/buf = 256 rows x 64B), B dbuf [32K,48K)
// (8KB/buf = 128 rows x 64B).  Swizzle (R12-verified, conflicts=0): 16B slot
// s at row r holds k-chunk s^((r>>1)&3); stage skb=(lane&3)^((lane>>3)&3),
// srow=lane>>2; read slot = l4^((l15>>1)&3).  2-way banks = free (m136).
//
// Schedule (R10 protocol re-derived; A halves = row 0-127/128-255 = wave wr's
// region; B staging halves = col 0-63/64-127 = wave wc's region):
//   p0: stage Ah1(t+1,IDLE) |BAR| rd amh0-m23; mmac(0,0); rd b1(n23)   |BAR|
//   p1: (no stage)          |BAR| mmac(0,1); rd amh1-m01               |BAR|
//   p2: stage Bh0+Bh1(t+2,live) |BAR| rd amh1-m23; mmac(1,1); VM2/VM0  |BAR|
//   p3: stage Ah0(t+2,live) |BAR| mmac(1,0); shadow rd b0,amh0-m01(t+1)|BAR|
// RAW: all t+1 stages drained by VM2@p2(t) (FIFO: leaves only Bh0/Bh1(t+2))
//   + p2-end barrier BEFORE p3 shadow reads (issuer-drain + common-barrier).
// WAR: B-half reads (b0@p3-shadow consumed mmac00@p0; b1@p0 consumed
//   mmac01@p1) lgkm-complete by p1-end -> B stages at p2 OK.  A-half reads
//   complete by p2-end (amh1-m23 lgkm before mmac11@p2) -> Ah0 stage at p3
//   OK.  Ah1 stages into the IDLE buffer (no WAR).
// Outstanding: enter t with 4 {Bh0,Bh1,Ah0}(t+1); p0 +2; p2 +2 -> 8, VM2
//   drains 6 oldest (all t+1); p3 +2 -> 4.  Prologue: 6(t0)+4(t1), VM4.
// ---------------------------------------------------------------------------
__global__ __launch_bounds__(256, 2) void qgemm_kernel(const bf16_t* __restrict__ A,
                                                       const bf16_t* __restrict__ Bt,
                                                       const float* __restrict__ bias,
                                                       float* __restrict__ C) {
    constexpr int M = 8192, N = 4096, K = 4096;
    constexpr int NT = K / 32;
    extern __shared__ __align__(16) char lds[];

    const int tid = threadIdx.x;
    const int w = tid >> 6;  // wave 0..3
    const int lane = tid & 63;
    const int l15 = lane & 15, l4 = lane >> 4;
    const int wr = w >> 1, wc = w & 1;  // 2 x 2 wave grid

    // XCD-aware swizzle (1024 wgs = 8*128, bijective)
    const int wg = blockIdx.x;
    const int swz = (wg & 7) * 128 + (wg >> 3);
    const int brow = (swz >> 5) * 256;  // 32 row-tiles
    const int bcol = (swz & 31) * 128;  // 32 col-tiles

    const int srow = lane >> 2;                   // row within 16-row group
    const int skb = (lane & 3) ^ ((lane >> 3) & 3);
    const int rslot = (l4 ^ ((l15 >> 1) & 3)) & 3;

    // panel-major staging: half chunks are contiguous in global memory
    auto stageA = [&](int buf, int h, int tt) {
#pragma unroll
        for (int q = 0; q < 2; ++q) {
            const int row = h * 128 + q * 64 + w * 16 + srow;
            const bf16_t* src = A + (size_t)tt * (M * 32) + (size_t)(brow + row) * 32 +
                                skb * 8;
            GLD16(src, lds + buf * 16384 + h * 8192 + q * 4096 + w * 1024);
        }
    };
    auto stageB = [&](int buf, int h, int tt) {
        const int row = h * 64 + w * 16 + srow;
        const bf16_t* src = Bt + (size_t)tt * (N * 32) + (size_t)(bcol + row) * 32 +
                            skb * 8;
        GLD16(src, lds + 32768 + buf * 8192 + h * 4096 + w * 1024);
    };

    f32x4 acc[8][4] = {};
    bf16x8 a[4], b0[2], b1[2];

    // A frag: wave reads ONLY its wr half; row = wr*128 + mh*64 + m*16 + l15
    auto ldAm = [&](int buf, int mh, int m) {
        const int row = wr * 128 + mh * 64 + m * 16 + l15;
        a[m] = *(const bf16x8*)(lds + buf * 16384 + row * 64 + rslot * 16);
    };
    // B frags: wave reads ONLY its wc half; pair nh -> frags n=nh*2+{0,1}
    auto ldB = [&](int buf, int nh, bf16x8(&b)[2]) {
#pragma unroll
        for (int n = 0; n < 2; ++n) {
            const int row = wc * 64 + nh * 32 + n * 16 + l15;
            b[n] = *(const bf16x8*)(lds + 32768 + buf * 8192 + row * 64 + rslot * 16);
        }
    };
    auto mmac = [&](int mh, int nh, bf16x8(&b)[2]) {
        __builtin_amdgcn_s_setprio(1);
#pragma unroll
        for (int m = 0; m < 4; ++m)
#pragma unroll
            for (int n = 0; n < 2; ++n)
                acc[mh * 4 + m][nh * 2 + n] = __builtin_amdgcn_mfma_f32_16x16x32_bf16(
                    a[m], b[n], acc[mh * 4 + m][nh * 2 + n], 0, 0, 0);
        __builtin_amdgcn_s_setprio(0);
    };

    // prologue: tile0 full (6 loads, buf0) + tile1's Bh0/Bh1/Ah0 (4, buf1);
    // VM4 drains tile0, leaves tile1's 4; BAR; preload b0/amh0-m01.
    stageA(0, 0, 0);
    stageA(0, 1, 0);
    stageB(0, 0, 0);
    stageB(0, 1, 0);
    stageB(1, 0, 1);
    stageB(1, 1, 1);
    stageA(1, 0, 1);
    WAIT_VM4();
    BAR();
    ldB(0, 0, b0);
    ldAm(0, 0, 0);
    ldAm(0, 0, 1);

    for (int tt = 0; tt < NT; ++tt) {
        const int cur = tt & 1;
        // phase 0: (mh0,nh0); stage A h1 of t+1 (IDLE buf)
        if (tt + 1 < NT) stageA(cur ^ 1, 1, tt + 1);
        BAR();
        ldAm(cur, 0, 2);
        ldAm(cur, 0, 3);
        mmac(0, 0, b0);
        ldB(cur, 1, b1);
        BAR();
        // phase 1: (mh0,nh1)
        BAR();
        mmac(0, 1, b1);
        ldAm(cur, 1, 0);
        ldAm(cur, 1, 1);
        BAR();
        // phase 2: (mh1,nh1); stage both B halves of t+2 (live); counted drain
        if (tt + 2 < NT) {
            stageB(cur, 0, tt + 2);
            stageB(cur, 1, tt + 2);
        }
        BAR();
        ldAm(cur, 1, 2);
        ldAm(cur, 1, 3);
        mmac(1, 1, b1);
        if (tt + 2 < NT) {
            WAIT_VM2();  // leaves Bh0/Bh1(t+2); ALL of t+1 landed
        } else {
            WAIT_VM0();  // tail
        }
        BAR();
        // phase 3: (mh1,nh0); stage A h0 of t+2 (live); shadow preload t+1
        if (tt + 2 < NT) stageA(cur, 0, tt + 2);
        BAR();
        mmac(1, 0, b0);
        if (tt + 1 < NT) {
            ldB(cur ^ 1, 0, b0);
            ldAm(cur ^ 1, 0, 0);
            ldAm(cur ^ 1, 0, 1);
        }
        BAR();
    }

    // epilogue: C/D layout col = lane&15, row = (lane>>4)*4 + i
#pragma unroll
    for (int n = 0; n < 4; ++n) {
        const int col = bcol + wc * 64 + n * 16 + l15;
        const float bv = bias[col];
#pragma unroll
        for (int m = 0; m < 8; ++m) {
            const int row0 = brow + wr * 128 + m * 16 + l4 * 4;
            const f32x4 v = acc[m][n];
#pragma unroll
            for (int i = 0; i < 4; ++i)
                C[(size_t)(row0 + i) * N + col] = v[i] + bv;
        }
    }
}

// ---------------------------------------------------------------------------
extern "C" void kernel_launch(void* const* d_in, const int* in_sizes, int n_in,
                              void* d_out, int out_size, void* d_ws, size_t ws_size,
                              hipStream_t stream) {
    const float* x = (const float*)d_in[0];
    const float* Wa = (const float*)d_in[1];
    const float* Wb = (const float*)d_in[2];
    const float* Wc = (const float*)d_in[3];
    const float* Wd = (const float*)d_in[4];
    const float* bias = (const float*)d_in[5];
    float* out = (float*)d_out;

    const int M = 8192, N = 4096, K = 4096;

    bf16_t* xbT = (bf16_t*)d_ws;        // panel-major [K/32][M][32]
    bf16_t* MtT = xbT + (size_t)M * K;  // panel-major [K/32][N][32]

    cvt_x_kernel<<<4096, 256, 0, stream>>>(x, xbT);
    pack_w_kernel<<<dim3(64, 64), 256, 0, stream>>>(Wa, Wb, Wc, Wd, MtT);

    (void)hipFuncSetAttribute((const void*)qgemm_kernel,
                              hipFuncAttributeMaxDynamicSharedMemorySize, 49152);
    qgemm_kernel<<<dim3((M / 256) * (N / 128)), 256, 49152, stream>>>(xbT, MtT, bias, out);
}

// Round 14
// 307.349 us; speedup vs baseline: 7.7862x; 1.0270x over previous
//
#include <hip/hip_runtime.h>
#include <hip/hip_bf16.h>
#include <cstdint>
#include <cstddef>

typedef __bf16 bf16_t;
typedef __bf16 bf16x4 __attribute__((ext_vector_type(4)));
typedef __bf16 bf16x8 __attribute__((ext_vector_type(8)));
typedef float f32x4 __attribute__((ext_vector_type(4)));
typedef float f32x16 __attribute__((ext_vector_type(16)));

#define GLD16(src, dst)                                                       \
    __builtin_amdgcn_global_load_lds(                                         \
        (const __attribute__((address_space(1))) void*)(src),                 \
        (__attribute__((address_space(3))) void*)(dst), 16, 0, 0)

// s_barrier WITH compiler memory fence (R8 lesson).
#define BAR() asm volatile("s_barrier" ::: "memory")
#define WAIT_VM4() asm volatile("s_waitcnt vmcnt(4)" ::: "memory")
#define WAIT_VM6() asm volatile("s_waitcnt vmcnt(6)" ::: "memory")
#define WAIT_VM0() asm volatile("s_waitcnt vmcnt(0)" ::: "memory")

// ---------------------------------------------------------------------------
// x fp32 -> bf16, vectorized (G13)
// ---------------------------------------------------------------------------
__global__ __launch_bounds__(256) void cvt_x_kernel(const float* __restrict__ x,
                                                    bf16_t* __restrict__ xb, int n4) {
    int idx = blockIdx.x * blockDim.x + threadIdx.x;
    int stride = gridDim.x * blockDim.x;
    const f32x4* xv = (const f32x4*)x;
    bf16x4* ov = (bf16x4*)xb;
    for (int i = idx; i < n4; i += stride) {
        f32x4 v = xv[i];
        bf16x4 o;
        o[0] = (bf16_t)v[0];
        o[1] = (bf16_t)v[1];
        o[2] = (bf16_t)v[2];
        o[3] = (bf16_t)v[3];
        ov[i] = o;
    }
}

// ---------------------------------------------------------------------------
// Build Mt[n][k] (bf16, [N][K]) from the quaternion Hamilton block structure.
// ---------------------------------------------------------------------------
__global__ __launch_bounds__(256) void pack_w_kernel(const float* __restrict__ Wa,
                                                     const float* __restrict__ Wb,
                                                     const float* __restrict__ Wc,
                                                     const float* __restrict__ Wd,
                                                     bf16_t* __restrict__ Mt) {
    __shared__ float tile[64][65];
    const int kb = blockIdx.x * 64;
    const int nb = blockIdx.y * 64;
    const int i = kb >> 10;
    const int j = nb >> 10;

    const float* W[4] = {Wa, Wb, Wc, Wd};
    const int srcIdx[4][4] = {{0, 1, 2, 3}, {1, 0, 3, 2}, {2, 3, 0, 1}, {3, 2, 1, 0}};
    const float sgn[4][4] = {{1.f, 1.f, 1.f, 1.f},
                             {-1.f, 1.f, -1.f, 1.f},
                             {-1.f, 1.f, 1.f, -1.f},
                             {-1.f, -1.f, 1.f, 1.f}};
    const float* Ws = W[srcIdx[i][j]];
    const float s = sgn[i][j];

    const int kq = kb & 1023;
    const int nq = nb & 1023;
    const int tx = threadIdx.x & 63;
    const int ty = threadIdx.x >> 6;

    for (int r = ty; r < 64; r += 4)
        tile[r][tx] = Ws[(size_t)(kq + r) * 1024 + (nq + tx)];
    __syncthreads();
    for (int r = ty; r < 64; r += 4)
        Mt[(size_t)(nb + r) * 4096 + (kb + tx)] = (bf16_t)(s * tile[tx][r]);
}

// ---------------------------------------------------------------------------
// 256x256 GEMM, R10's proven 4-phase protocol, MFMA shape 32x32x16.
// 512 threads = 8 waves (2Mx4N), per-wave 128x64.  BK=64, 128B rows.
// LDS 128 KiB: A dbuf [0,64K), B dbuf [64K,128K); half = [128 rows][64 k].
// T2 swizzle: LDS[r][slot s] = global k-chunk s^(r&7); stage skb =
// (lane&7)^(lane>>3), srow = lane>>3 (linear gload_lds dest, rule 21);
// read slot for k-chunk kc at row R: kc^(R&7), R&7 = l31&7.
//
// 32x32x16 geometry (why: pipe rate 2382-2495 TF vs 16x16's 2075-2176,
// m06/m119 -> mandatory pipe time 132us -> 111us; LDS bytes unchanged):
//   per wave: 4 m-frags (rows wr*128 + mi*32) x 2 n-frags (cols nh*128 +
//   wc*32) of 32x32; 4 K-steps of 16.  nh = B STAGING HALF (fixes R6's
//   misaligned-half race).  A frag (m,ks): 1 ds_read_b128 at row
//   mh*64+m*32+l31, k-chunk ks*2+l5.  C/D: col=lane&31,
//   row=(reg&3)+8*(reg>>2)+4*(lane>>5) [HW-verified m74/m101].  A/B k-feed
//   uses the SAME slot->k map for both operands -> result exact for ANY
//   hardware k-order (permutation cancels in the contraction).
//
// Schedule/sync = R10 byte-identical (passing, race-free):
//   p0: stage Ah1(t+1,IDLE) |BAR| rd amh0-m1; mmac(0,0); rd b1        |BAR|
//   p1: stage Bh0(t+2,live) |BAR| mmac(0,1); rd amh1-m0               |BAR|
//   p2: stage Bh1(t+2,live) |BAR| rd amh1-m1; mmac(1,1); VM4(/VM0)    |BAR|
//   p3: stage Ah0(t+2,live) |BAR| mmac(1,0); shadow rd b0,amh0-m0(t+1)|BAR|
// VM4@p2 FIFO-drains ALL of t+1 (leaves Bh0/Bh1(t+2)) + p2-end barrier =>
// p3 shadow reads sound for every wave (issuer-drain + common-barrier rule).
// WAR: b0 consumed mmac00@p0 -> Bh0 stage@p1 OK; b1 consumed mmac01@p1 ->
// Bh1 stage@p2 OK; A-half reads done by p2-end -> Ah0 stage@p3 OK; Ah1 ->
// idle buf.  Tails exactly as R10.
// ---------------------------------------------------------------------------
__global__ __launch_bounds__(512, 2) void qgemm_kernel(const bf16_t* __restrict__ A,
                                                       const bf16_t* __restrict__ Bt,
                                                       const float* __restrict__ bias,
                                                       float* __restrict__ C) {
    constexpr int N = 4096, K = 4096;
    constexpr int NT = K / 64;
    extern __shared__ __align__(16) char lds[];

    const int tid = threadIdx.x;
    const int w = tid >> 6;
    const int lane = tid & 63;
    const int l31 = lane & 31, l5 = lane >> 5;
    const int wr = w >> 2, wc = w & 3;  // 2 x 4 wave grid

    // XCD-aware swizzle (512 = 8*64, bijective)
    const int wg = blockIdx.x;
    const int swz = (wg & 7) * 64 + (wg >> 3);
    const int brow = (swz >> 4) * 256;  // 32 tile rows
    const int bcol = (swz & 15) * 256;  // 16 tile cols

    const int srow = lane >> 3;
    const int skb = (lane & 7) ^ (lane >> 3);

    auto stageA = [&](int buf, int h, int tt) {
#pragma unroll
        for (int q = 0; q < 2; ++q) {
            const bf16_t* src = A + (size_t)(brow + h * 128 + w * 16 + q * 8 + srow) * K +
                                tt * 64 + skb * 8;
            GLD16(src, lds + buf * 32768 + h * 16384 + w * 2048 + q * 1024);
        }
    };
    auto stageB = [&](int buf, int h, int tt) {
#pragma unroll
        for (int q = 0; q < 2; ++q) {
            const bf16_t* src = Bt + (size_t)(bcol + h * 128 + w * 16 + q * 8 + srow) * K +
                                tt * 64 + skb * 8;
            GLD16(src, lds + 65536 + buf * 32768 + h * 16384 + w * 2048 + q * 1024);
        }
    };

    f32x16 acc[4][2] = {};   // [mh*2+m][nh]
    bf16x8 a[2][4];          // a[m][ks] for the CURRENT mh
    bf16x8 b0[4], b1[4];     // b[ks] per staging half

    // A frag set (4 reads): rows wr*128 + mh*64 + m*32 + l31, k-chunks ks*2+l5
    auto ldA32 = [&](int buf, int mh, int m) {
#pragma unroll
        for (int ks = 0; ks < 4; ++ks) {
            const int R = mh * 64 + m * 32 + l31;
            a[m][ks] = *(const bf16x8*)(lds + buf * 32768 + wr * 16384 + R * 128 +
                                        (((ks * 2 + l5) ^ (R & 7)) & 7) * 16);
        }
    };
    // B frag set (4 reads): nh = staging half; col (local) = wc*32 + l31
    auto ldB32 = [&](int buf, int nh, bf16x8(&b)[4]) {
#pragma unroll
        for (int ks = 0; ks < 4; ++ks) {
            const int R = wc * 32 + l31;
            b[ks] = *(const bf16x8*)(lds + 65536 + buf * 32768 + nh * 16384 + R * 128 +
                                     (((ks * 2 + l5) ^ (R & 7)) & 7) * 16);
        }
    };
    auto mmac = [&](int mh, int nh, bf16x8(&b)[4]) {
        __builtin_amdgcn_s_setprio(1);
#pragma unroll
        for (int m = 0; m < 2; ++m)
#pragma unroll
            for (int ks = 0; ks < 4; ++ks)
                acc[mh * 2 + m][nh] = __builtin_amdgcn_mfma_f32_32x32x16_bf16(
                    a[m][ks], b[ks], acc[mh * 2 + m][nh], 0, 0, 0);
        __builtin_amdgcn_s_setprio(0);
    };

    // prologue: tile0 full (8 loads, buf0) + tile1's Bh0/Bh1/Ah0 (6, buf1);
    // VM6 drains tile0 (issuer drain), BAR (common), then preload reads.
    stageA(0, 0, 0);
    stageA(0, 1, 0);
    stageB(0, 0, 0);
    stageB(0, 1, 0);
    stageB(1, 0, 1);
    stageB(1, 1, 1);
    stageA(1, 0, 1);
    WAIT_VM6();
    BAR();
    ldB32(0, 0, b0);
    ldA32(0, 0, 0);  // amh0-m0

    for (int tt = 0; tt < NT; ++tt) {
        const int cur = tt & 1;
        // phase 0: (mh0,nh0); stage A h1 of t+1 (IDLE buf)
        if (tt + 1 < NT) stageA(cur ^ 1, 1, tt + 1);
        BAR();
        ldA32(cur, 0, 1);  // amh0-m1
        mmac(0, 0, b0);
        ldB32(cur, 1, b1);  // under mmac00's pipe drain
        BAR();
        // phase 1: (mh0,nh1); stage B h0 of t+2 (live buf)
        if (tt + 2 < NT) stageB(cur, 0, tt + 2);
        BAR();
        mmac(0, 1, b1);
        ldA32(cur, 1, 0);  // amh1-m0 (a[0] regs free after mmac01 issues)
        BAR();
        // phase 2: (mh1,nh1); stage B h1 of t+2 (live buf); counted drain
        if (tt + 2 < NT) stageB(cur, 1, tt + 2);
        BAR();
        ldA32(cur, 1, 1);  // amh1-m1
        mmac(1, 1, b1);
        if (tt + 2 < NT) {
            WAIT_VM4();  // leaves Bh0/Bh1(t+2); ALL of t+1 landed
        } else {
            WAIT_VM0();  // tail
        }
        BAR();
        // phase 3: (mh1,nh0); stage A h0 of t+2 (live buf); shadow preload t+1
        if (tt + 2 < NT) stageA(cur, 0, tt + 2);
        BAR();
        mmac(1, 0, b0);
        if (tt + 1 < NT) {
            ldB32(cur ^ 1, 0, b0);  // b0(t+1): drained@p2 + common barrier
            ldA32(cur ^ 1, 0, 0);   // amh0(t+1)-m0 (a regs free after mmac10)
        }
        BAR();
    }

    // epilogue: 32x32 C/D: col = lane&31, row = (reg&3)+8*(reg>>2)+4*l5
#pragma unroll
    for (int nh = 0; nh < 2; ++nh) {
        const int col = bcol + nh * 128 + wc * 32 + l31;
        const float bv = bias[col];
#pragma unroll
        for (int mi = 0; mi < 4; ++mi) {
            const f32x16 v = acc[mi][nh];
            const int row0 = brow + wr * 128 + mi * 32 + 4 * l5;
#pragma unroll
            for (int reg = 0; reg < 16; ++reg) {
                const int row = row0 + (reg & 3) + 8 * (reg >> 2);
                C[(size_t)row * N + col] = v[reg] + bv;
            }
        }
    }
}

// ---------------------------------------------------------------------------
extern "C" void kernel_launch(void* const* d_in, const int* in_sizes, int n_in,
                              void* d_out, int out_size, void* d_ws, size_t ws_size,
                              hipStream_t stream) {
    const float* x = (const float*)d_in[0];
    const float* Wa = (const float*)d_in[1];
    const float* Wb = (const float*)d_in[2];
    const float* Wc = (const float*)d_in[3];
    const float* Wd = (const float*)d_in[4];
    const float* bias = (const float*)d_in[5];
    float* out = (float*)d_out;

    const int M = 8192, N = 4096, K = 4096;

    bf16_t* xb = (bf16_t*)d_ws;       // [M][K] bf16
    bf16_t* Mt = xb + (size_t)M * K;  // [N][K] bf16

    cvt_x_kernel<<<4096, 256, 0, stream>>>(x, xb, (M * K) / 4);
    pack_w_kernel<<<dim3(64, 64), 256, 0, stream>>>(Wa, Wb, Wc, Wd, Mt);

    (void)hipFuncSetAttribute((const void*)qgemm_kernel,
                              hipFuncAttributeMaxDynamicSharedMemorySize, 131072);
    qgemm_kernel<<<dim3((M / 256) * (N / 256)), 512, 131072, stream>>>(xb, Mt, bias, out);
}

// Round 15
// 283.551 us; speedup vs baseline: 8.4397x; 1.0839x over previous
//
#include <hip/hip_runtime.h>
#include <hip/hip_bf16.h>
#include <cstdint>
#include <cstddef>

typedef __bf16 bf16_t;
typedef __bf16 bf16x4 __attribute__((ext_vector_type(4)));
typedef __bf16 bf16x8 __attribute__((ext_vector_type(8)));
typedef float f32x4 __attribute__((ext_vector_type(4)));

#define GLD16(src, dst)                                                       \
    __builtin_amdgcn_global_load_lds(                                         \
        (const __attribute__((address_space(1))) void*)(src),                 \
        (__attribute__((address_space(3))) void*)(dst), 16, 0, 0)

// s_barrier WITH compiler memory fence (R8 lesson).
#define BAR() asm volatile("s_barrier" ::: "memory")
#define WAIT_VM4() asm volatile("s_waitcnt vmcnt(4)" ::: "memory")
#define WAIT_VM6() asm volatile("s_waitcnt vmcnt(6)" ::: "memory")
#define WAIT_VM0() asm volatile("s_waitcnt vmcnt(0)" ::: "memory")

// ---------------------------------------------------------------------------
// x fp32 -> bf16, vectorized (G13)
// ---------------------------------------------------------------------------
__global__ __launch_bounds__(256) void cvt_x_kernel(const float* __restrict__ x,
                                                    bf16_t* __restrict__ xb, int n4) {
    int idx = blockIdx.x * blockDim.x + threadIdx.x;
    int stride = gridDim.x * blockDim.x;
    const f32x4* xv = (const f32x4*)x;
    bf16x4* ov = (bf16x4*)xb;
    for (int i = idx; i < n4; i += stride) {
        f32x4 v = xv[i];
        bf16x4 o;
        o[0] = (bf16_t)v[0];
        o[1] = (bf16_t)v[1];
        o[2] = (bf16_t)v[2];
        o[3] = (bf16_t)v[3];
        ov[i] = o;
    }
}

// ---------------------------------------------------------------------------
// Build Mt[n][k] (bf16, [N][K]) from the quaternion Hamilton block structure.
// ---------------------------------------------------------------------------
__global__ __launch_bounds__(256) void pack_w_kernel(const float* __restrict__ Wa,
                                                     const float* __restrict__ Wb,
                                                     const float* __restrict__ Wc,
                                                     const float* __restrict__ Wd,
                                                     bf16_t* __restrict__ Mt) {
    __shared__ float tile[64][65];
    const int kb = blockIdx.x * 64;
    const int nb = blockIdx.y * 64;
    const int i = kb >> 10;
    const int j = nb >> 10;

    const float* W[4] = {Wa, Wb, Wc, Wd};
    const int srcIdx[4][4] = {{0, 1, 2, 3}, {1, 0, 3, 2}, {2, 3, 0, 1}, {3, 2, 1, 0}};
    const float sgn[4][4] = {{1.f, 1.f, 1.f, 1.f},
                             {-1.f, 1.f, -1.f, 1.f},
                             {-1.f, 1.f, 1.f, -1.f},
                             {-1.f, -1.f, 1.f, 1.f}};
    const float* Ws = W[srcIdx[i][j]];
    const float s = sgn[i][j];

    const int kq = kb & 1023;
    const int nq = nb & 1023;
    const int tx = threadIdx.x & 63;
    const int ty = threadIdx.x >> 6;

    for (int r = ty; r < 64; r += 4)
        tile[r][tx] = Ws[(size_t)(kq + r) * 1024 + (nq + tx)];
    __syncthreads();
    for (int r = ty; r < 64; r += 4)
        Mt[(size_t)(nb + r) * 4096 + (kb + tx)] = (bf16_t)(s * tile[tx][r]);
}

// ---------------------------------------------------------------------------
// 256x256 GEMM, R10's proven 4-phase protocol (16x16x32 MFMA), with ONE
// change: mmac issues K-chunk c OUTERMOST.
//
// R14 diagnosis: five schedules x two MFMA shapes all plateau at MfmaUtil
// ~50%.  Common factor: mmac's c-innermost order emits back-to-back MFMAs
// on the SAME accumulator (c=1 reads c=0's result) -> every 2nd MFMA stalls
// the dependent-issue latency -> ~50% pipe rate regardless of schedule.
// c-outermost gives 8 independent MFMAs (distinct acc regs) between any
// accumulator reuse (~39cy of issue >= latency) -> latency hidden.
// Numerics identical: each acc[m][n] still accumulates c0 then c1.
//
// Everything else (staging, T2 swizzle, phases, barriers, VM4@p2 counted
// drain, shadow preloads, epilogue) is byte-identical to the passing R10.
// ---------------------------------------------------------------------------
__global__ __launch_bounds__(512, 2) void qgemm_kernel(const bf16_t* __restrict__ A,
                                                       const bf16_t* __restrict__ Bt,
                                                       const float* __restrict__ bias,
                                                       float* __restrict__ C) {
    constexpr int N = 4096, K = 4096;
    constexpr int NT = K / 64;
    extern __shared__ __align__(16) char lds[];

    const int tid = threadIdx.x;
    const int w = tid >> 6;
    const int lane = tid & 63;
    const int l15 = lane & 15, l4 = lane >> 4;
    const int wr = w >> 2, wc = w & 3;  // 2 x 4 wave grid

    // XCD-aware swizzle (512 = 8*64, bijective)
    const int wg = blockIdx.x;
    const int swz = (wg & 7) * 64 + (wg >> 3);
    const int brow = (swz >> 4) * 256;  // 32 tile rows
    const int bcol = (swz & 15) * 256;  // 16 tile cols

    // staging: LDS stores k-block' = kb ^ (row&7); dest linear, global source
    // k-block for lane slot (lane&7) at row (lane>>3) is the inverse perm:
    const int srow = lane >> 3;
    const int skb = (lane & 7) ^ (lane >> 3);

    auto stageA = [&](int buf, int h, int tt) {
#pragma unroll
        for (int q = 0; q < 2; ++q) {
            const bf16_t* src = A + (size_t)(brow + h * 128 + w * 16 + q * 8 + srow) * K +
                                tt * 64 + skb * 8;
            GLD16(src, lds + buf * 32768 + h * 16384 + w * 2048 + q * 1024);
        }
    };
    auto stageB = [&](int buf, int h, int tt) {
#pragma unroll
        for (int q = 0; q < 2; ++q) {
            const bf16_t* src = Bt + (size_t)(bcol + h * 128 + w * 16 + q * 8 + srow) * K +
                                tt * 64 + skb * 8;
            GLD16(src, lds + 65536 + buf * 32768 + h * 16384 + w * 2048 + q * 1024);
        }
    };

    f32x4 acc[8][4] = {};
    bf16x8 a[4][2], b0[2][2], b1[2][2];

    // one A m-frag (2 reads): row = wr-half, mh sub-half, frag m
    auto ldAm = [&](int buf, int mh, int m) {
#pragma unroll
        for (int c = 0; c < 2; ++c)
            a[m][c] = *(const bf16x8*)(lds + buf * 32768 + wr * 16384 +
                                       (mh * 64 + m * 16 + l15) * 128 +
                                       ((c * 4 + l4) ^ (l15 & 7)) * 16);
    };
    // B frags: nh selects the STAGING half; wave cols = nh*128 + wc*32 + n*16
    auto ldB = [&](int buf, int nh, bf16x8(&b)[2][2]) {
#pragma unroll
        for (int n = 0; n < 2; ++n)
#pragma unroll
            for (int c = 0; c < 2; ++c)
                b[n][c] = *(const bf16x8*)(lds + 65536 + buf * 32768 + nh * 16384 +
                                           (wc * 32 + n * 16 + l15) * 128 +
                                           ((c * 4 + l4) ^ (l15 & 7)) * 16);
    };
    // c OUTERMOST: 8 independent MFMAs between accumulator reuses.
    auto mmac = [&](int mh, int nh, bf16x8(&b)[2][2]) {
        __builtin_amdgcn_s_setprio(1);
#pragma unroll
        for (int c = 0; c < 2; ++c)
#pragma unroll
            for (int m = 0; m < 4; ++m)
#pragma unroll
                for (int n = 0; n < 2; ++n)
                    acc[mh * 4 + m][nh * 2 + n] = __builtin_amdgcn_mfma_f32_16x16x32_bf16(
                        a[m][c], b[n][c], acc[mh * 4 + m][nh * 2 + n], 0, 0, 0);
        __builtin_amdgcn_s_setprio(0);
    };

    // prologue: tile0 full (8 loads, buf0) + tile1's Bh0/Bh1/Ah0 (6, buf1);
    // VM6 drains tile0 (issuer drain), BAR (common), then preload reads.
    stageA(0, 0, 0);
    stageA(0, 1, 0);
    stageB(0, 0, 0);
    stageB(0, 1, 0);
    stageB(1, 0, 1);
    stageB(1, 1, 1);
    stageA(1, 0, 1);
    WAIT_VM6();
    BAR();
    ldB(0, 0, b0);
    ldAm(0, 0, 0);
    ldAm(0, 0, 1);

    for (int tt = 0; tt < NT; ++tt) {
        const int cur = tt & 1;
        // phase 0: (mh0,nh0); stage A h1 of t+1 (IDLE buf)
        if (tt + 1 < NT) stageA(cur ^ 1, 1, tt + 1);
        BAR();
        ldAm(cur, 0, 2);
        ldAm(cur, 0, 3);
        mmac(0, 0, b0);
        ldB(cur, 1, b1);  // Bh1(t): reads run under mmac00's pipe drain
        BAR();
        // phase 1: (mh0,nh1); stage B h0 of t+2 (live buf)
        if (tt + 2 < NT) stageB(cur, 0, tt + 2);
        BAR();
        mmac(0, 1, b1);
        ldAm(cur, 1, 0);  // amh1 m0,m1
        ldAm(cur, 1, 1);
        BAR();
        // phase 2: (mh1,nh1); stage B h1 of t+2 (live buf); counted drain
        if (tt + 2 < NT) stageB(cur, 1, tt + 2);
        BAR();
        ldAm(cur, 1, 2);
        ldAm(cur, 1, 3);
        mmac(1, 1, b1);
        // VM4: FIFO-drains everything except Bh0/Bh1(t+2) -> ALL of t+1
        // landed; p2-end BAR makes it common knowledge.
        if (tt + 2 < NT) {
            WAIT_VM4();
        } else {
            WAIT_VM0();  // tail
        }
        BAR();
        // phase 3: (mh1,nh0); stage A h0 of t+2 (live buf); shadow preload t+1
        if (tt + 2 < NT) stageA(cur, 0, tt + 2);
        BAR();
        mmac(1, 0, b0);
        if (tt + 1 < NT) {
            ldB(cur ^ 1, 0, b0);  // b0(t+1): drained@p2 + common barrier
            ldAm(cur ^ 1, 0, 0);  // amh0(t+1) m0,m1
            ldAm(cur ^ 1, 0, 1);
        }
        BAR();
    }

    // epilogue: C/D layout col = lane&15, row = (lane>>4)*4 + i.
    // B mapping: global n -> col = (n>>1)*128 + wc*32 + (n&1)*16
#pragma unroll
    for (int n = 0; n < 4; ++n) {
        const int col = bcol + (n >> 1) * 128 + wc * 32 + (n & 1) * 16 + l15;
        const float bv = bias[col];
#pragma unroll
        for (int m = 0; m < 8; ++m) {
            const int row0 = brow + wr * 128 + m * 16 + l4 * 4;
            const f32x4 v = acc[m][n];
#pragma unroll
            for (int i = 0; i < 4; ++i)
                C[(size_t)(row0 + i) * N + col] = v[i] + bv;
        }
    }
}

// ---------------------------------------------------------------------------
extern "C" void kernel_launch(void* const* d_in, const int* in_sizes, int n_in,
                              void* d_out, int out_size, void* d_ws, size_t ws_size,
                              hipStream_t stream) {
    const float* x = (const float*)d_in[0];
    const float* Wa = (const float*)d_in[1];
    const float* Wb = (const float*)d_in[2];
    const float* Wc = (const float*)d_in[3];
    const float* Wd = (const float*)d_in[4];
    const float* bias = (const float*)d_in[5];
    float* out = (float*)d_out;

    const int M = 8192, N = 4096, K = 4096;

    bf16_t* xb = (bf16_t*)d_ws;       // [M][K] bf16
    bf16_t* Mt = xb + (size_t)M * K;  // [N][K] bf16

    cvt_x_kernel<<<4096, 256, 0, stream>>>(x, xb, (M * K) / 4);
    pack_w_kernel<<<dim3(64, 64), 256, 0, stream>>>(Wa, Wb, Wc, Wd, Mt);

    (void)hipFuncSetAttribute((const void*)qgemm_kernel,
                              hipFuncAttributeMaxDynamicSharedMemorySize, 131072);
    qgemm_kernel<<<dim3((M / 256) * (N / 256)), 512, 131072, stream>>>(xb, Mt, bias, out);
}

// Round 16
// 282.277 us; speedup vs baseline: 8.4778x; 1.0045x over previous
//
#include <hip/hip_runtime.h>
#include <hip/hip_bf16.h>
#include <cstdint>
#include <cstddef>

typedef __bf16 bf16_t;
typedef __bf16 bf16x4 __attribute__((ext_vector_type(4)));
typedef __bf16 bf16x8 __attribute__((ext_vector_type(8)));
typedef float f32x4 __attribute__((ext_vector_type(4)));

#define GLD16(src, dst)                                                       \
    __builtin_amdgcn_global_load_lds(                                         \
        (const __attribute__((address_space(1))) void*)(src),                 \
        (__attribute__((address_space(3))) void*)(dst), 16, 0, 0)

// s_barrier WITH compiler memory fence (R8 lesson).
#define BAR() asm volatile("s_barrier" ::: "memory")
#define WAIT_VM4() asm volatile("s_waitcnt vmcnt(4)" ::: "memory")
#define WAIT_VM6() asm volatile("s_waitcnt vmcnt(6)" ::: "memory")
#define WAIT_VM0() asm volatile("s_waitcnt vmcnt(0)" ::: "memory")

// ---------------------------------------------------------------------------
// x fp32 -> bf16, vectorized (G13)
// ---------------------------------------------------------------------------
__global__ __launch_bounds__(256) void cvt_x_kernel(const float* __restrict__ x,
                                                    bf16_t* __restrict__ xb, int n4) {
    int idx = blockIdx.x * blockDim.x + threadIdx.x;
    int stride = gridDim.x * blockDim.x;
    const f32x4* xv = (const f32x4*)x;
    bf16x4* ov = (bf16x4*)xb;
    for (int i = idx; i < n4; i += stride) {
        f32x4 v = xv[i];
        bf16x4 o;
        o[0] = (bf16_t)v[0];
        o[1] = (bf16_t)v[1];
        o[2] = (bf16_t)v[2];
        o[3] = (bf16_t)v[3];
        ov[i] = o;
    }
}

// ---------------------------------------------------------------------------
// Build Mt[n][k] (bf16, [N][K]) from the quaternion Hamilton block structure.
// ---------------------------------------------------------------------------
__global__ __launch_bounds__(256) void pack_w_kernel(const float* __restrict__ Wa,
                                                     const float* __restrict__ Wb,
                                                     const float* __restrict__ Wc,
                                                     const float* __restrict__ Wd,
                                                     bf16_t* __restrict__ Mt) {
    __shared__ float tile[64][65];
    const int kb = blockIdx.x * 64;
    const int nb = blockIdx.y * 64;
    const int i = kb >> 10;
    const int j = nb >> 10;

    const float* W[4] = {Wa, Wb, Wc, Wd};
    const int srcIdx[4][4] = {{0, 1, 2, 3}, {1, 0, 3, 2}, {2, 3, 0, 1}, {3, 2, 1, 0}};
    const float sgn[4][4] = {{1.f, 1.f, 1.f, 1.f},
                             {-1.f, 1.f, -1.f, 1.f},
                             {-1.f, 1.f, 1.f, -1.f},
                             {-1.f, -1.f, 1.f, 1.f}};
    const float* Ws = W[srcIdx[i][j]];
    const float s = sgn[i][j];

    const int kq = kb & 1023;
    const int nq = nb & 1023;
    const int tx = threadIdx.x & 63;
    const int ty = threadIdx.x >> 6;

    for (int r = ty; r < 64; r += 4)
        tile[r][tx] = Ws[(size_t)(kq + r) * 1024 + (nq + tx)];
    __syncthreads();
    for (int r = ty; r < 64; r += 4)
        Mt[(size_t)(nb + r) * 4096 + (kb + tx)] = (bf16_t)(s * tile[tx][r]);
}

// ---------------------------------------------------------------------------
// 256x256 GEMM, R10/R15's proven 4-phase protocol, UNROLLED 2 K-tiles/iter.
//
// R15 post-mortem: 7 schedule/shape variants all pin at 244-248us; m201's
// structurally-identical reference runs 3300cy/K-tile vs our 4575.  Remaining
// delta: m201's loop is unrolled with COMPILE-TIME buffer indices; ours
// threads a runtime cur=tt&1 through every LDS address -> 24 ds_read + 4
// stage dests per tile are VALU-computed (VALUBusy 23% ~= 1050cy/tile) and,
// with 2 lockstepped waves/SIMD, that VALU cannot hide under MFMA.  This
// round: macro-expand the R15 tile body at buf=0 and buf=1 (NT even), so all
// LDS offsets fold to base+immediate.  Schedule/sync byte-identical per tile.
// ---------------------------------------------------------------------------
__global__ __launch_bounds__(512, 2) void qgemm_kernel(const bf16_t* __restrict__ A,
                                                       const bf16_t* __restrict__ Bt,
                                                       const float* __restrict__ bias,
                                                       float* __restrict__ C) {
    constexpr int N = 4096, K = 4096;
    constexpr int NT = K / 64;
    extern __shared__ __align__(16) char lds[];

    const int tid = threadIdx.x;
    const int w = tid >> 6;
    const int lane = tid & 63;
    const int l15 = lane & 15, l4 = lane >> 4;
    const int wr = w >> 2, wc = w & 3;  // 2 x 4 wave grid

    // XCD-aware swizzle (512 = 8*64, bijective)
    const int wg = blockIdx.x;
    const int swz = (wg & 7) * 64 + (wg >> 3);
    const int brow = (swz >> 4) * 256;  // 32 tile rows
    const int bcol = (swz & 15) * 256;  // 16 tile cols

    // staging: LDS stores k-block' = kb ^ (row&7); dest linear, global source
    // k-block for lane slot (lane&7) at row (lane>>3) is the inverse perm:
    const int srow = lane >> 3;
    const int skb = (lane & 7) ^ (lane >> 3);

    auto stageA = [&](int buf, int h, int tt) {
#pragma unroll
        for (int q = 0; q < 2; ++q) {
            const bf16_t* src = A + (size_t)(brow + h * 128 + w * 16 + q * 8 + srow) * K +
                                tt * 64 + skb * 8;
            GLD16(src, lds + buf * 32768 + h * 16384 + w * 2048 + q * 1024);
        }
    };
    auto stageB = [&](int buf, int h, int tt) {
#pragma unroll
        for (int q = 0; q < 2; ++q) {
            const bf16_t* src = Bt + (size_t)(bcol + h * 128 + w * 16 + q * 8 + srow) * K +
                                tt * 64 + skb * 8;
            GLD16(src, lds + 65536 + buf * 32768 + h * 16384 + w * 2048 + q * 1024);
        }
    };

    f32x4 acc[8][4] = {};
    bf16x8 a[4][2], b0[2][2], b1[2][2];

    // one A m-frag (2 reads): row = wr-half, mh sub-half, frag m
    auto ldAm = [&](int buf, int mh, int m) {
#pragma unroll
        for (int c = 0; c < 2; ++c)
            a[m][c] = *(const bf16x8*)(lds + buf * 32768 + wr * 16384 +
                                       (mh * 64 + m * 16 + l15) * 128 +
                                       ((c * 4 + l4) ^ (l15 & 7)) * 16);
    };
    // B frags: nh selects the STAGING half; wave cols = nh*128 + wc*32 + n*16
    auto ldB = [&](int buf, int nh, bf16x8(&b)[2][2]) {
#pragma unroll
        for (int n = 0; n < 2; ++n)
#pragma unroll
            for (int c = 0; c < 2; ++c)
                b[n][c] = *(const bf16x8*)(lds + 65536 + buf * 32768 + nh * 16384 +
                                           (wc * 32 + n * 16 + l15) * 128 +
                                           ((c * 4 + l4) ^ (l15 & 7)) * 16);
    };
    // c outermost (R15): 8 independent MFMAs between accumulator reuses.
    auto mmac = [&](int mh, int nh, bf16x8(&b)[2][2]) {
        __builtin_amdgcn_s_setprio(1);
#pragma unroll
        for (int c = 0; c < 2; ++c)
#pragma unroll
            for (int m = 0; m < 4; ++m)
#pragma unroll
                for (int n = 0; n < 2; ++n)
                    acc[mh * 4 + m][nh * 2 + n] = __builtin_amdgcn_mfma_f32_16x16x32_bf16(
                        a[m][c], b[n][c], acc[mh * 4 + m][nh * 2 + n], 0, 0, 0);
        __builtin_amdgcn_s_setprio(0);
    };

// R15 tile body with LITERAL buffer index CUR (compile-time after inlining).
#define TILE_BODY(CUR, TT)                                                    \
    {                                                                         \
        const int tt = (TT);                                                  \
        /* p0: (mh0,nh0); stage A h1 of t+1 (IDLE buf) */                     \
        if (tt + 1 < NT) stageA((CUR) ^ 1, 1, tt + 1);                        \
        BAR();                                                                \
        ldAm((CUR), 0, 2);                                                    \
        ldAm((CUR), 0, 3);                                                    \
        mmac(0, 0, b0);                                                       \
        ldB((CUR), 1, b1);                                                    \
        BAR();                                                                \
        /* p1: (mh0,nh1); stage B h0 of t+2 (live buf) */                     \
        if (tt + 2 < NT) stageB((CUR), 0, tt + 2);                            \
        BAR();                                                                \
        mmac(0, 1, b1);                                                       \
        ldAm((CUR), 1, 0);                                                    \
        ldAm((CUR), 1, 1);                                                    \
        BAR();                                                                \
        /* p2: (mh1,nh1); stage B h1 of t+2 (live buf); counted drain */      \
        if (tt + 2 < NT) stageB((CUR), 1, tt + 2);                            \
        BAR();                                                                \
        ldAm((CUR), 1, 2);                                                    \
        ldAm((CUR), 1, 3);                                                    \
        mmac(1, 1, b1);                                                       \
        if (tt + 2 < NT) {                                                    \
            WAIT_VM4();                                                       \
        } else {                                                              \
            WAIT_VM0();                                                       \
        }                                                                     \
        BAR();                                                                \
        /* p3: (mh1,nh0); stage A h0 of t+2 (live buf); shadow preload */     \
        if (tt + 2 < NT) stageA((CUR), 0, tt + 2);                            \
        BAR();                                                                \
        mmac(1, 0, b0);                                                       \
        if (tt + 1 < NT) {                                                    \
            ldB((CUR) ^ 1, 0, b0);                                            \
            ldAm((CUR) ^ 1, 0, 0);                                            \
            ldAm((CUR) ^ 1, 0, 1);                                            \
        }                                                                     \
        BAR();                                                                \
    }

    // prologue: tile0 full (8 loads, buf0) + tile1's Bh0/Bh1/Ah0 (6, buf1);
    // VM6 drains tile0 (issuer drain), BAR (common), then preload reads.
    stageA(0, 0, 0);
    stageA(0, 1, 0);
    stageB(0, 0, 0);
    stageB(0, 1, 0);
    stageB(1, 0, 1);
    stageB(1, 1, 1);
    stageA(1, 0, 1);
    WAIT_VM6();
    BAR();
    ldB(0, 0, b0);
    ldAm(0, 0, 0);
    ldAm(0, 0, 1);

    // main loop: 2 K-tiles per iteration, buf indices compile-time 0/1
    for (int it = 0; it < NT / 2; ++it) {
        TILE_BODY(0, 2 * it);
        TILE_BODY(1, 2 * it + 1);
    }
#undef TILE_BODY

    // epilogue: C/D layout col = lane&15, row = (lane>>4)*4 + i.
    // B mapping: global n -> col = (n>>1)*128 + wc*32 + (n&1)*16
#pragma unroll
    for (int n = 0; n < 4; ++n) {
        const int col = bcol + (n >> 1) * 128 + wc * 32 + (n & 1) * 16 + l15;
        const float bv = bias[col];
#pragma unroll
        for (int m = 0; m < 8; ++m) {
            const int row0 = brow + wr * 128 + m * 16 + l4 * 4;
            const f32x4 v = acc[m][n];
#pragma unroll
            for (int i = 0; i < 4; ++i)
                C[(size_t)(row0 + i) * N + col] = v[i] + bv;
        }
    }
}

// ---------------------------------------------------------------------------
extern "C" void kernel_launch(void* const* d_in, const int* in_sizes, int n_in,
                              void* d_out, int out_size, void* d_ws, size_t ws_size,
                              hipStream_t stream) {
    const float* x = (const float*)d_in[0];
    const float* Wa = (const float*)d_in[1];
    const float* Wb = (const float*)d_in[2];
    const float* Wc = (const float*)d_in[3];
    const float* Wd = (const float*)d_in[4];
    const float* bias = (const float*)d_in[5];
    float* out = (float*)d_out;

    const int M = 8192, N = 4096, K = 4096;

    bf16_t* xb = (bf16_t*)d_ws;       // [M][K] bf16
    bf16_t* Mt = xb + (size_t)M * K;  // [N][K] bf16

    cvt_x_kernel<<<4096, 256, 0, stream>>>(x, xb, (M * K) / 4);
    pack_w_kernel<<<dim3(64, 64), 256, 0, stream>>>(Wa, Wb, Wc, Wd, Mt);

    (void)hipFuncSetAttribute((const void*)qgemm_kernel,
                              hipFuncAttributeMaxDynamicSharedMemorySize, 131072);
    qgemm_kernel<<<dim3((M / 256) * (N / 256)), 512, 131072, stream>>>(xb, Mt, bias, out);
}